// Round 18
// baseline (203.742 us; speedup 1.0000x reference)
//
#include <hip/hip_runtime.h>
#include <hip/hip_bf16.h>
#include <math.h>

// PNA layer, R18: R13 (verified, 60.1us) + edge/h-stream software pipeline.
// R16 proved BW 2.06 TB/s is reachable with prefetch in flight (but spilled);
// R17 showed LDS-staging costs too much occupancy. R18: pipeline ONLY the 64MB
// edge stream + h (36 regs, no LDS), u8/v/j gathered direct per tile (L2-hot).
// sched_barrier(0) pins the issue point; value-pins after tiles bound the wait.
//   u = h@W1 + b_pre -> offset-int8 (scale 16); v = h@W2 (bf16)
//   per group (16 nodes): acc = mfma32x32x16(ea,W3,0); e = relu(acc+u/16-8+v)
//   agg=[mean,max,min,std]; y1 = relu([h,agg]@Wfull + b1); out = y1@Wp2 + b2 + h
// MFMA layouts: 16x16x32 (m89-verified), 32x32x16 C/D (m74/m101-verified).

#define N_NODES 65536
#define NBLK (N_NODES / 16)       // 4096 groups
#define NITER 4
#define GRID_MAIN (NBLK / NITER)  // 1024 persistent blocks
#define GRID_PREP (NBLK + 64)
#define ASTRIDE 348   // A_lds row stride (u16)
#define YSTRIDE 76    // y1_lds row stride (u16)

typedef float f32x4 __attribute__((ext_vector_type(4)));
typedef float f32x16 __attribute__((ext_vector_type(16)));
typedef short s16x8 __attribute__((ext_vector_type(8)));
typedef unsigned short us4 __attribute__((ext_vector_type(4)));
typedef int i32x4 __attribute__((ext_vector_type(4)));

__device__ __forceinline__ unsigned short f2bf(float f) {     // manual RNE
    union { float f; unsigned int u; } v; v.f = f;
    unsigned int r = v.u + 0x7fffu + ((v.u >> 16) & 1u);
    return (unsigned short)(r >> 16);
}
__device__ __forceinline__ unsigned short f2bfh(float f) {    // compiler cvt
    __hip_bfloat16 b = __float2bfloat16(f);
    union { __hip_bfloat16 b; unsigned short u; } v; v.b = b; return v.u;
}
__device__ __forceinline__ float bf2f(unsigned short u) {
    union { unsigned int u; float f; } v; v.u = ((unsigned int)u) << 16; return v.f;
}
__device__ __forceinline__ unsigned char enc_u8(float x) {    // offset-int8, scale 16
    int q = __float2int_rn(x * 16.f) + 128;
    q = q < 0 ? 0 : (q > 255 ? 255 : q);
    return (unsigned char)q;
}

// ---------------- prep: u/v via MFMA (blocks < NBLK) + weight transpose ----------------
__global__ __launch_bounds__(256) void k_prep(const float* __restrict__ h,
                                              const float* __restrict__ Wpre,
                                              const float* __restrict__ b_pre,
                                              const float* __restrict__ Wp1,
                                              const float* __restrict__ Wp2,
                                              unsigned char* __restrict__ u8,
                                              unsigned short* __restrict__ vbf,
                                              unsigned short* __restrict__ wfullT,
                                              unsigned short* __restrict__ w3T,
                                              unsigned short* __restrict__ wp2T,
                                              float c1, float c2) {
    int t = threadIdx.x;
    if (blockIdx.x >= NBLK) {
        int c = blockIdx.x - NBLK;     // output col 0..63
        for (int k = t; k < 320; k += 256) {
            float v;
            if (k < 64) v = Wp1[k * 64 + c];
            else {
                int kk = k - 64;
                v = Wp1[(64 + kk) * 64 + c] + c1 * Wp1[(320 + kk) * 64 + c]
                                            + c2 * Wp1[(576 + kk) * 64 + c];
            }
            wfullT[c * 320 + k] = f2bf(v);
        }
        if (t < 16)              w3T[c * 16 + t]         = f2bf(Wpre[(128 + t) * 64 + c]);
        if (t >= 64 && t < 128)  wp2T[c * 64 + (t - 64)] = f2bf(Wp2[(t - 64) * 64 + c]);
        return;
    }

    // ---- uv blocks: [u|v] = h @ [W1|W2], 16 nodes, 4 waves x 32 cols ----
    __shared__ unsigned short hl[16 * 68];
    int lane = t & 63;
    int wv = __builtin_amdgcn_readfirstlane(t) >> 6;   // wave id (uniform)
    int c = lane & 15, g = lane >> 4;
    int node0 = blockIdx.x * 16;
    {
        int r = t >> 4, q = t & 15;
        float4 hv = *((const float4*)(h + (size_t)node0 * 64) + t);
        us4 o;
        o.x = f2bfh(hv.x); o.y = f2bfh(hv.y); o.z = f2bfh(hv.z); o.w = f2bfh(hv.w);
        *(us4*)&hl[r * 68 + q * 4] = o;
    }
    s16x8 bf[2][2];
    int woff = (wv < 2) ? 0 : 64;
    #pragma unroll
    for (int i2 = 0; i2 < 2; ++i2) {
        int wcol = ((wv & 1) * 32) + i2 * 16 + c;
        #pragma unroll
        for (int ks = 0; ks < 2; ++ks) {
            #pragma unroll
            for (int j = 0; j < 8; ++j)
                bf[i2][ks][j] = (short)f2bfh(Wpre[(woff + ks * 32 + g * 8 + j) * 64 + wcol]);
        }
    }
    __syncthreads();
    f32x4 acc0 = {0.f, 0.f, 0.f, 0.f}, acc1 = {0.f, 0.f, 0.f, 0.f};
    #pragma unroll
    for (int ks = 0; ks < 2; ++ks) {
        s16x8 a = *(const s16x8*)&hl[c * 68 + ks * 32 + g * 8];
        acc0 = __builtin_amdgcn_mfma_f32_16x16x32_bf16(a, bf[0][ks], acc0, 0, 0, 0);
        acc1 = __builtin_amdgcn_mfma_f32_16x16x32_bf16(a, bf[1][ks], acc1, 0, 0, 0);
    }
    #pragma unroll
    for (int i2 = 0; i2 < 2; ++i2) {
        int dcol = ((wv & 1) * 32) + i2 * 16 + c;
        const f32x4& av = i2 ? acc1 : acc0;
        if (wv < 2) {
            float bp = b_pre[dcol];
            #pragma unroll
            for (int i = 0; i < 4; ++i) {
                int row = g * 4 + i;
                u8[(size_t)(node0 + row) * 64 + dcol] = enc_u8(av[i] + bp);
            }
        } else {
            #pragma unroll
            for (int i = 0; i < 4; ++i) {
                int row = g * 4 + i;
                vbf[(size_t)(node0 + row) * 64 + dcol] = f2bfh(av[i]);
            }
        }
    }
}

// ---------------- fused main: persistent, NITER edge-pipelined groups ----------------
__global__ __launch_bounds__(256, 4) void k_main(
    const float* __restrict__ h,
    const float* __restrict__ edge_attr,
    const int* __restrict__ nbr_idx,
    const float* __restrict__ b_post1,
    const float* __restrict__ b_post2,
    const unsigned char* __restrict__ u8,       // [N][64] offset-int8 (4 MB, L2-fit)
    const unsigned short* __restrict__ vbf,     // [N][64] bf16
    const unsigned short* __restrict__ wfullT,  // [64][320] bf16 (L2-resident)
    const unsigned short* __restrict__ w3T,     // [64][16]
    const unsigned short* __restrict__ wp2T,    // [64][64]
    float* __restrict__ out) {
    __shared__ unsigned short A_lds[16 * ASTRIDE];   // 11136 B
    __shared__ unsigned short y1_lds[16 * YSTRIDE];  // 2432 B  -> 13568 B total

    int t = threadIdx.x;
    int lane = t & 63;
    int wv = __builtin_amdgcn_readfirstlane(t) >> 6;    // wave id (uniform)
    int c = lane & 15;          // 16x16 frag col / A-row
    int g = lane >> 4;          // 16x16 k-group
    int l32 = lane & 31;        // 32x32 frag row/col
    int h2 = lane >> 5;         // 32x32 k-half
    int ct = wv & 1;            // 32-col tile (uniform)
    int wr = wv >> 1;           // row-tile base (uniform)
    int colb = ct * 32 + l32;   // pretrans output col
    unsigned cbu = (unsigned)colb;         // byte offset within 64B u8 row
    unsigned cb2 = (unsigned)(colb * 2);   // byte offset within 128B v row
    int col16 = wv * 16 + c;    // post1/post2 output col
    int grp0 = blockIdx.x * NITER;

    s16x8 w3b = *(const s16x8*)&w3T[colb * 16 + h2 * 8];
    float b1c = b_post1[col16];
    float b2c = b_post2[col16];
    const unsigned char* ub = u8;

    // ---------- prologue: edges + h for group grp0 ----------
    float4 xaC[4], xbC[4];
    {
        const char* eb = (const char*)edge_attr
                       + ((size_t)grp0 * 256 + wr * 32 + l32) * 64 + h2 * 32;
        #pragma unroll
        for (int k = 0; k < 4; ++k) {
            xaC[k] = *(const float4*)(eb + k * 4096);
            xbC[k] = *(const float4*)(eb + k * 4096 + 16);
        }
        float4 hv = *((const float4*)(h + (size_t)grp0 * 1024) + t);
        int r = t >> 4, q = t & 15;
        us4 o;
        o.x = f2bfh(hv.x); o.y = f2bfh(hv.y); o.z = f2bfh(hv.z); o.w = f2bfh(hv.w);
        *(us4*)&A_lds[r * ASTRIDE + q * 4] = o;
    }

    #pragma unroll
    for (int it = 0; it < NITER; ++it) {
        int grp = grp0 + it;
        int node16 = grp * 16;
        size_t node0 = (size_t)node16;
        const bool pf = (it + 1 < NITER);

        // ---- issue next group's edge stream + h (the 64MB stream in flight) ----
        float4 xaN[4], xbN[4];
        float4 hN = {0.f, 0.f, 0.f, 0.f};
        if (pf) {
            const char* ebn = (const char*)edge_attr
                            + ((size_t)(grp + 1) * 256 + wr * 32 + l32) * 64 + h2 * 32;
            #pragma unroll
            for (int k = 0; k < 4; ++k) {
                xaN[k] = *(const float4*)(ebn + k * 4096);
                xbN[k] = *(const float4*)(ebn + k * 4096 + 16);
            }
            hN = *((const float4*)(h + (size_t)(grp + 1) * 1024) + t);
            __builtin_amdgcn_sched_barrier(0);   // pin the ISSUE point (no sinking)
        }

        const char* vb = (const char*)vbf + ((unsigned)node16 << 7)
                       + (unsigned)(wr * 256) + cb2;

        // ---- tiles: 4x 32x32x16 MFMA + stats (u8/v/j direct, L2-hot) ----
#define TILEC(IT, XA, XB) {                                                    \
    int rt = wr + 2 * (IT);                                                    \
    const int* nbq = nbr_idx + node16 * 16 + rt * 32 + 4 * h2;                 \
    i32x4 jq0 = *(const i32x4*)(nbq);                                          \
    i32x4 jq1 = *(const i32x4*)(nbq + 8);                                      \
    i32x4 jq2 = *(const i32x4*)(nbq + 16);                                     \
    i32x4 jq3 = *(const i32x4*)(nbq + 24);                                     \
    s16x8 a;                                                                   \
    a[0] = (short)f2bfh(XA.x); a[1] = (short)f2bfh(XA.y);                      \
    a[2] = (short)f2bfh(XA.z); a[3] = (short)f2bfh(XA.w);                      \
    a[4] = (short)f2bfh(XB.x); a[5] = (short)f2bfh(XB.y);                      \
    a[6] = (short)f2bfh(XB.z); a[7] = (short)f2bfh(XB.w);                      \
    f32x16 acc = {};                                                           \
    acc = __builtin_amdgcn_mfma_f32_32x32x16_bf16(a, w3b, acc, 0, 0, 0);       \
    float uf[16];                                                              \
    _Pragma("unroll")                                                          \
    for (int i = 0; i < 4; ++i) {                                              \
        uf[i]      = (float)ub[((unsigned)jq0[i] << 6) + cbu];                 \
        uf[4 + i]  = (float)ub[((unsigned)jq1[i] << 6) + cbu];                 \
        uf[8 + i]  = (float)ub[((unsigned)jq2[i] << 6) + cbu];                 \
        uf[12 + i] = (float)ub[((unsigned)jq3[i] << 6) + cbu];                 \
    }                                                                          \
    float vm0 = bf2f(*(const unsigned short*)(vb + (IT) * 512)) - 8.f;         \
    float vm1 = bf2f(*(const unsigned short*)(vb + (IT) * 512 + 128)) - 8.f;   \
    float e0  = fmaxf(fmaf(uf[0],  0.0625f, acc[0]  + vm0), 0.f);              \
    float e1  = fmaxf(fmaf(uf[1],  0.0625f, acc[1]  + vm0), 0.f);              \
    float e2  = fmaxf(fmaf(uf[2],  0.0625f, acc[2]  + vm0), 0.f);              \
    float e3  = fmaxf(fmaf(uf[3],  0.0625f, acc[3]  + vm0), 0.f);              \
    float e4  = fmaxf(fmaf(uf[4],  0.0625f, acc[4]  + vm0), 0.f);              \
    float e5  = fmaxf(fmaf(uf[5],  0.0625f, acc[5]  + vm0), 0.f);              \
    float e6  = fmaxf(fmaf(uf[6],  0.0625f, acc[6]  + vm0), 0.f);              \
    float e7  = fmaxf(fmaf(uf[7],  0.0625f, acc[7]  + vm0), 0.f);              \
    float e8  = fmaxf(fmaf(uf[8],  0.0625f, acc[8]  + vm1), 0.f);              \
    float e9  = fmaxf(fmaf(uf[9],  0.0625f, acc[9]  + vm1), 0.f);              \
    float e10 = fmaxf(fmaf(uf[10], 0.0625f, acc[10] + vm1), 0.f);              \
    float e11 = fmaxf(fmaf(uf[11], 0.0625f, acc[11] + vm1), 0.f);              \
    float e12 = fmaxf(fmaf(uf[12], 0.0625f, acc[12] + vm1), 0.f);              \
    float e13 = fmaxf(fmaf(uf[13], 0.0625f, acc[13] + vm1), 0.f);              \
    float e14 = fmaxf(fmaf(uf[14], 0.0625f, acc[14] + vm1), 0.f);              \
    float e15 = fmaxf(fmaf(uf[15], 0.0625f, acc[15] + vm1), 0.f);              \
    float s1a = ((e0 + e1) + (e2 + e3)) + ((e4 + e5) + (e6 + e7));             \
    float s2a = fmaf(e0, e0, fmaf(e1, e1, fmaf(e2, e2, e3 * e3)))              \
              + fmaf(e4, e4, fmaf(e5, e5, fmaf(e6, e6, e7 * e7)));             \
    float mxa = fmaxf(fmaxf(fmaxf(e0, e1), fmaxf(e2, e3)),                     \
                      fmaxf(fmaxf(e4, e5), fmaxf(e6, e7)));                    \
    float mna = fminf(fminf(fminf(e0, e1), fminf(e2, e3)),                     \
                      fminf(fminf(e4, e5), fminf(e6, e7)));                    \
    float s1b = ((e8 + e9) + (e10 + e11)) + ((e12 + e13) + (e14 + e15));       \
    float s2b = fmaf(e8, e8, fmaf(e9, e9, fmaf(e10, e10, e11 * e11)))          \
              + fmaf(e12, e12, fmaf(e13, e13, fmaf(e14, e14, e15 * e15)));     \
    float mxb = fmaxf(fmaxf(fmaxf(e8, e9), fmaxf(e10, e11)),                   \
                      fmaxf(fmaxf(e12, e13), fmaxf(e14, e15)));                \
    float mnb = fminf(fminf(fminf(e8, e9), fminf(e10, e11)),                   \
                      fminf(fminf(e12, e13), fminf(e14, e15)));                \
    s1a += __shfl_xor(s1a, 32); s2a += __shfl_xor(s2a, 32);                    \
    mxa = fmaxf(mxa, __shfl_xor(mxa, 32)); mna = fminf(mna, __shfl_xor(mna, 32)); \
    s1b += __shfl_xor(s1b, 32); s2b += __shfl_xor(s2b, 32);                    \
    mxb = fmaxf(mxb, __shfl_xor(mxb, 32)); mnb = fminf(mnb, __shfl_xor(mnb, 32)); \
    float S1 = h2 ? s1b : s1a;                                                 \
    float S2 = h2 ? s2b : s2a;                                                 \
    float MX = h2 ? mxb : mxa;                                                 \
    float MN = h2 ? mnb : mna;                                                 \
    float M  = S1 * 0.0625f;                                                   \
    float SD = sqrtf(fmaxf(fmaf(-M, M, S2 * 0.0625f), 0.f) + 1e-5f);           \
    unsigned short* pd = &A_lds[(2 * rt + h2) * ASTRIDE + 64 + colb];          \
    pd[0]   = f2bfh(M);                                                        \
    pd[64]  = f2bfh(MX);                                                       \
    pd[128] = f2bfh(MN);                                                       \
    pd[192] = f2bfh(SD);                                                       \
}
        TILEC(0, xaC[0], xbC[0])
        TILEC(1, xaC[1], xbC[1])
        TILEC(2, xaC[2], xbC[2])
        TILEC(3, xaC[3], xbC[3])
#undef TILEC

        // ---- pin prefetched values AFTER tiles (wait lands post-compute) ----
        if (pf) {
            #pragma unroll
            for (int k = 0; k < 4; ++k) {
                asm volatile("" :: "v"(xaN[k].x), "v"(xaN[k].y), "v"(xaN[k].z), "v"(xaN[k].w));
                asm volatile("" :: "v"(xbN[k].x), "v"(xbN[k].y), "v"(xbN[k].z), "v"(xbN[k].w));
            }
            asm volatile("" :: "v"(hN.x), "v"(hN.y), "v"(hN.z), "v"(hN.w));
        }

        // ---- hoist post1 weight loads (drain with barrier) ----
        s16x8 wf[10];
        #pragma unroll
        for (int ks = 0; ks < 10; ++ks)
            wf[ks] = *(const s16x8*)&wfullT[col16 * 320 + ks * 32 + g * 8];
        __syncthreads();   // barrier(1): agg + h staging visible

        // ---- post1: y1 = relu([h,agg]@Wfull + b1), K=320 ----
        {
            f32x4 y1 = {0.f, 0.f, 0.f, 0.f};
            #pragma unroll
            for (int ks = 0; ks < 10; ++ks) {
                s16x8 a = *(const s16x8*)&A_lds[c * ASTRIDE + ks * 32 + g * 8];
                y1 = __builtin_amdgcn_mfma_f32_16x16x32_bf16(a, wf[ks], y1, 0, 0, 0);
            }
            #pragma unroll
            for (int i = 0; i < 4; ++i)
                y1_lds[(g * 4 + i) * YSTRIDE + col16] = f2bfh(fmaxf(y1[i] + b1c, 0.f));
        }
        s16x8 wp0 = *(const s16x8*)&wp2T[col16 * 64 + 0 * 32 + g * 8];
        s16x8 wp1 = *(const s16x8*)&wp2T[col16 * 64 + 1 * 32 + g * 8];
        __syncthreads();   // barrier(2): y1 visible; A_lds reads done

        // ---- stage h(it+1) into A_lds (A free until next post1) ----
        if (pf) {
            int r = t >> 4, q = t & 15;
            us4 o;
            o.x = f2bfh(hN.x); o.y = f2bfh(hN.y); o.z = f2bfh(hN.z); o.w = f2bfh(hN.w);
            *(us4*)&A_lds[r * ASTRIDE + q * 4] = o;
        }

        // ---- post2 + residual ----
        {
            f32x4 o = {0.f, 0.f, 0.f, 0.f};
            s16x8 a0 = *(const s16x8*)&y1_lds[c * YSTRIDE + 0 * 32 + g * 8];
            s16x8 a1 = *(const s16x8*)&y1_lds[c * YSTRIDE + 1 * 32 + g * 8];
            o = __builtin_amdgcn_mfma_f32_16x16x32_bf16(a0, wp0, o, 0, 0, 0);
            o = __builtin_amdgcn_mfma_f32_16x16x32_bf16(a1, wp1, o, 0, 0, 0);
            #pragma unroll
            for (int i = 0; i < 4; ++i) {
                int r = g * 4 + i;
                out[(node0 + r) * 64 + col16] =
                    o[i] + b2c + h[(node0 + r) * 64 + col16];
            }
        }

        // ---- rotate edge registers (SSA under full unroll) ----
        if (pf) {
            #pragma unroll
            for (int k = 0; k < 4; ++k) { xaC[k] = xaN[k]; xbC[k] = xbN[k]; }
        }
    }
}

extern "C" void kernel_launch(void* const* d_in, const int* in_sizes, int n_in,
                              void* d_out, int out_size, void* d_ws, size_t ws_size,
                              hipStream_t stream) {
    const float* h         = (const float*)d_in[0];
    const float* edge_attr = (const float*)d_in[1];
    const int*   nbr_idx   = (const int*)d_in[2];
    const float* W_pre     = (const float*)d_in[3];
    const float* b_pre     = (const float*)d_in[4];
    const float* W_post1   = (const float*)d_in[5];
    const float* b_post1   = (const float*)d_in[6];
    const float* W_post2   = (const float*)d_in[7];
    const float* b_post2   = (const float*)d_in[8];
    float* out = (float*)d_out;

    size_t need = (size_t)N_NODES * 64           // u8
                + (size_t)N_NODES * 64 * 2       // v bf16
                + (64 * 320 + 64 * 16 + 64 * 64) * 2;
    if (ws_size < need) return;   // ~12.05 MiB
    unsigned char*  u8p    = (unsigned char*)d_ws;                      // [N][64] u8
    unsigned short* vbf    = (unsigned short*)(u8p + (size_t)N_NODES * 64);  // [N][64] bf16
    unsigned short* wfullT = vbf + (size_t)N_NODES * 64;                // [64][320]
    unsigned short* w3T    = wfullT + 64 * 320;                         // [64][16]
    unsigned short* wp2T   = w3T + 64 * 16;                             // [64][64]

    double ld = log(16.0 + 1.0);                          // log(D+1)
    const double AVG = 2.302585092994046;
    float c1 = (float)(ld / AVG);
    float c2 = (float)(AVG / ld);

    k_prep<<<GRID_PREP, 256, 0, stream>>>(h, W_pre, b_pre, W_post1, W_post2,
                                          u8p, vbf, wfullT, w3T, wp2T, c1, c2);
    k_main<<<GRID_MAIN, 256, 0, stream>>>(h, edge_attr, nbr_idx, b_post1, b_post2,
                                          u8p, vbf, wfullT, w3T, wp2T, out);
}

// Round 19
// 72.527 us; speedup vs baseline: 2.8092x; 2.8092x over previous
//
#include <hip/hip_runtime.h>
#include <hip/hip_bf16.h>
#include <math.h>

// PNA layer, R19: revert to R13 (verified 60.1us best) minus the pre-tile
// barrier: nbr_idx read direct from global per tile (verified in R18's TILEC),
// h staged into A_lds AFTER the tiles (only post1 needs it). One barrier less,
// tiles start at wave launch. Pipelining abandoned: R16/R17/R18 showed hipcc
// either spills prefetch state or loses occupancy to LDS staging.
//   u = h@W1 + b_pre -> offset-int8 (scale 16); v = h@W2 (bf16)
//   per 16-node block: acc = mfma32x32x16(ea,W3,0); e = relu(acc + u/16-8 + v)
//   agg=[mean,max,min,std]; y1 = relu([h,agg]@Wfull + b1); out = y1@Wp2 + b2 + h
// MFMA layouts: 16x16x32 (m89-verified), 32x32x16 C/D (m74/m101-verified).

#define N_NODES 65536
#define NBLK (N_NODES / 16)       // 4096 main/uv blocks
#define GRID_PREP (NBLK + 64)     // + 64 weight-transpose blocks
#define ASTRIDE 348   // A_lds row stride (u16)
#define YSTRIDE 76    // y1_lds row stride (u16)

typedef float f32x4 __attribute__((ext_vector_type(4)));
typedef float f32x16 __attribute__((ext_vector_type(16)));
typedef short s16x8 __attribute__((ext_vector_type(8)));
typedef unsigned short us4 __attribute__((ext_vector_type(4)));
typedef int i32x4 __attribute__((ext_vector_type(4)));

__device__ __forceinline__ unsigned short f2bf(float f) {     // manual RNE
    union { float f; unsigned int u; } v; v.f = f;
    unsigned int r = v.u + 0x7fffu + ((v.u >> 16) & 1u);
    return (unsigned short)(r >> 16);
}
__device__ __forceinline__ unsigned short f2bfh(float f) {    // compiler cvt
    __hip_bfloat16 b = __float2bfloat16(f);
    union { __hip_bfloat16 b; unsigned short u; } v; v.b = b; return v.u;
}
__device__ __forceinline__ float bf2f(unsigned short u) {
    union { unsigned int u; float f; } v; v.u = ((unsigned int)u) << 16; return v.f;
}
__device__ __forceinline__ unsigned char enc_u8(float x) {    // offset-int8, scale 16
    int q = __float2int_rn(x * 16.f) + 128;
    q = q < 0 ? 0 : (q > 255 ? 255 : q);
    return (unsigned char)q;
}

// ---------------- prep: u/v via MFMA (blocks < NBLK) + weight transpose ----------------
__global__ __launch_bounds__(256) void k_prep(const float* __restrict__ h,
                                              const float* __restrict__ Wpre,
                                              const float* __restrict__ b_pre,
                                              const float* __restrict__ Wp1,
                                              const float* __restrict__ Wp2,
                                              unsigned char* __restrict__ u8,
                                              unsigned short* __restrict__ vbf,
                                              unsigned short* __restrict__ wfullT,
                                              unsigned short* __restrict__ w3T,
                                              unsigned short* __restrict__ wp2T,
                                              float c1, float c2) {
    int t = threadIdx.x;
    if (blockIdx.x >= NBLK) {
        int c = blockIdx.x - NBLK;     // output col 0..63
        for (int k = t; k < 320; k += 256) {
            float v;
            if (k < 64) v = Wp1[k * 64 + c];
            else {
                int kk = k - 64;
                v = Wp1[(64 + kk) * 64 + c] + c1 * Wp1[(320 + kk) * 64 + c]
                                            + c2 * Wp1[(576 + kk) * 64 + c];
            }
            wfullT[c * 320 + k] = f2bf(v);
        }
        if (t < 16)              w3T[c * 16 + t]         = f2bf(Wpre[(128 + t) * 64 + c]);
        if (t >= 64 && t < 128)  wp2T[c * 64 + (t - 64)] = f2bf(Wp2[(t - 64) * 64 + c]);
        return;
    }

    // ---- uv blocks: [u|v] = h @ [W1|W2], 16 nodes, 4 waves x 32 cols ----
    __shared__ unsigned short hl[16 * 68];
    int lane = t & 63;
    int wv = __builtin_amdgcn_readfirstlane(t) >> 6;   // wave id (uniform)
    int c = lane & 15, g = lane >> 4;
    int node0 = blockIdx.x * 16;
    {
        int r = t >> 4, q = t & 15;
        float4 hv = *((const float4*)(h + (size_t)node0 * 64) + t);
        us4 o;
        o.x = f2bfh(hv.x); o.y = f2bfh(hv.y); o.z = f2bfh(hv.z); o.w = f2bfh(hv.w);
        *(us4*)&hl[r * 68 + q * 4] = o;
    }
    s16x8 bf[2][2];
    int woff = (wv < 2) ? 0 : 64;
    #pragma unroll
    for (int i2 = 0; i2 < 2; ++i2) {
        int wcol = ((wv & 1) * 32) + i2 * 16 + c;
        #pragma unroll
        for (int ks = 0; ks < 2; ++ks) {
            #pragma unroll
            for (int j = 0; j < 8; ++j)
                bf[i2][ks][j] = (short)f2bfh(Wpre[(woff + ks * 32 + g * 8 + j) * 64 + wcol]);
        }
    }
    __syncthreads();
    f32x4 acc0 = {0.f, 0.f, 0.f, 0.f}, acc1 = {0.f, 0.f, 0.f, 0.f};
    #pragma unroll
    for (int ks = 0; ks < 2; ++ks) {
        s16x8 a = *(const s16x8*)&hl[c * 68 + ks * 32 + g * 8];
        acc0 = __builtin_amdgcn_mfma_f32_16x16x32_bf16(a, bf[0][ks], acc0, 0, 0, 0);
        acc1 = __builtin_amdgcn_mfma_f32_16x16x32_bf16(a, bf[1][ks], acc1, 0, 0, 0);
    }
    #pragma unroll
    for (int i2 = 0; i2 < 2; ++i2) {
        int dcol = ((wv & 1) * 32) + i2 * 16 + c;
        const f32x4& av = i2 ? acc1 : acc0;
        if (wv < 2) {
            float bp = b_pre[dcol];
            #pragma unroll
            for (int i = 0; i < 4; ++i) {
                int row = g * 4 + i;
                u8[(size_t)(node0 + row) * 64 + dcol] = enc_u8(av[i] + bp);
            }
        } else {
            #pragma unroll
            for (int i = 0; i < 4; ++i) {
                int row = g * 4 + i;
                vbf[(size_t)(node0 + row) * 64 + dcol] = f2bfh(av[i]);
            }
        }
    }
}

// ---------------- fused main: one 16-node group per block ----------------
__global__ __launch_bounds__(256, 4) void k_main(
    const float* __restrict__ h,
    const float* __restrict__ edge_attr,
    const int* __restrict__ nbr_idx,
    const float* __restrict__ b_post1,
    const float* __restrict__ b_post2,
    const unsigned char* __restrict__ u8,       // [N][64] offset-int8 (4 MB, L2-fit)
    const unsigned short* __restrict__ vbf,     // [N][64] bf16
    const unsigned short* __restrict__ wfullT,  // [64][320] bf16 (L2-resident)
    const unsigned short* __restrict__ w3T,     // [64][16]
    const unsigned short* __restrict__ wp2T,    // [64][64]
    float* __restrict__ out) {
    __shared__ unsigned short A_lds[16 * ASTRIDE];   // 11136 B
    __shared__ unsigned short y1_lds[16 * YSTRIDE];  // 2432 B  -> 13568 B total

    int t = threadIdx.x;
    int lane = t & 63;
    int wv = __builtin_amdgcn_readfirstlane(t) >> 6;    // wave id (uniform)
    int c = lane & 15;          // 16x16 frag col / A-row
    int g = lane >> 4;          // 16x16 k-group
    int l32 = lane & 31;        // 32x32 frag row/col
    int h2 = lane >> 5;         // 32x32 k-half
    int ct = wv & 1;            // 32-col tile (uniform)
    int wr = wv >> 1;           // row-tile base (uniform)
    int colb = ct * 32 + l32;   // pretrans output col
    unsigned cbu = (unsigned)colb;         // byte offset within 64B u8 row
    unsigned cb2 = (unsigned)(colb * 2);   // byte offset within 128B v row
    int col16 = wv * 16 + c;    // post1/post2 output col
    int node16 = blockIdx.x * 16;
    size_t node0 = (size_t)node16;

    s16x8 w3b = *(const s16x8*)&w3T[colb * 16 + h2 * 8];
    float b1c = b_post1[col16];
    float b2c = b_post2[col16];

    const unsigned char* ub = u8;
    const char* vb = (const char*)vbf + ((unsigned)node16 << 7) + (unsigned)(wr * 256) + cb2;
    const char* eb = (const char*)edge_attr
                   + ((size_t)node16 * 16 + wr * 32 + l32) * 64 + h2 * 32;

    // ---- h load issued early (used after tiles, latency fully hidden) ----
    float4 hv = *((const float4*)(h + node0 * 64) + t);

    // ---- pretrans: 4x 32x32x16 MFMA tiles; NO barrier before (nbr direct) ----
    #pragma unroll
    for (int it = 0; it < 4; ++it) {
        int rt = wr + 2 * it;                    // row-tile 0..7 (uniform)

        // neighbor indices direct from global (half-wave-uniform 16B loads)
        const int* nbq = nbr_idx + node16 * 16 + rt * 32 + 4 * h2;
        i32x4 jq0 = *(const i32x4*)(nbq);
        i32x4 jq1 = *(const i32x4*)(nbq + 8);
        i32x4 jq2 = *(const i32x4*)(nbq + 16);
        i32x4 jq3 = *(const i32x4*)(nbq + 24);

        // A-frag from global fp32
        float4 x0 = *(const float4*)(eb + it * 4096);
        float4 x1 = *(const float4*)(eb + it * 4096 + 16);
        s16x8 a;
        a[0] = (short)f2bfh(x0.x); a[1] = (short)f2bfh(x0.y);
        a[2] = (short)f2bfh(x0.z); a[3] = (short)f2bfh(x0.w);
        a[4] = (short)f2bfh(x1.x); a[5] = (short)f2bfh(x1.y);
        a[6] = (short)f2bfh(x1.z); a[7] = (short)f2bfh(x1.w);

        f32x16 acc = {};
        acc = __builtin_amdgcn_mfma_f32_32x32x16_bf16(a, w3b, acc, 0, 0, 0);

        // gathered u8 (16 scalar 1B loads, in flight alongside the MFMA)
        float uf[16];
        #pragma unroll
        for (int i = 0; i < 4; ++i) {
            uf[i]      = (float)ub[((unsigned)jq0[i] << 6) + cbu];
            uf[4 + i]  = (float)ub[((unsigned)jq1[i] << 6) + cbu];
            uf[8 + i]  = (float)ub[((unsigned)jq2[i] << 6) + cbu];
            uf[12 + i] = (float)ub[((unsigned)jq3[i] << 6) + cbu];
        }
        float vm0 = bf2f(*(const unsigned short*)(vb + it * 512)) - 8.f;
        float vm1 = bf2f(*(const unsigned short*)(vb + it * 512 + 128)) - 8.f;

        // e = relu(acc + u + v) with u = uf/16 - 8 folded via fmaf
        float e0  = fmaxf(fmaf(uf[0],  0.0625f, acc[0]  + vm0), 0.f);
        float e1  = fmaxf(fmaf(uf[1],  0.0625f, acc[1]  + vm0), 0.f);
        float e2  = fmaxf(fmaf(uf[2],  0.0625f, acc[2]  + vm0), 0.f);
        float e3  = fmaxf(fmaf(uf[3],  0.0625f, acc[3]  + vm0), 0.f);
        float e4  = fmaxf(fmaf(uf[4],  0.0625f, acc[4]  + vm0), 0.f);
        float e5  = fmaxf(fmaf(uf[5],  0.0625f, acc[5]  + vm0), 0.f);
        float e6  = fmaxf(fmaf(uf[6],  0.0625f, acc[6]  + vm0), 0.f);
        float e7  = fmaxf(fmaf(uf[7],  0.0625f, acc[7]  + vm0), 0.f);
        float e8  = fmaxf(fmaf(uf[8],  0.0625f, acc[8]  + vm1), 0.f);
        float e9  = fmaxf(fmaf(uf[9],  0.0625f, acc[9]  + vm1), 0.f);
        float e10 = fmaxf(fmaf(uf[10], 0.0625f, acc[10] + vm1), 0.f);
        float e11 = fmaxf(fmaf(uf[11], 0.0625f, acc[11] + vm1), 0.f);
        float e12 = fmaxf(fmaf(uf[12], 0.0625f, acc[12] + vm1), 0.f);
        float e13 = fmaxf(fmaf(uf[13], 0.0625f, acc[13] + vm1), 0.f);
        float e14 = fmaxf(fmaf(uf[14], 0.0625f, acc[14] + vm1), 0.f);
        float e15 = fmaxf(fmaf(uf[15], 0.0625f, acc[15] + vm1), 0.f);

        float s1a = ((e0 + e1) + (e2 + e3)) + ((e4 + e5) + (e6 + e7));
        float s2a = fmaf(e0, e0, fmaf(e1, e1, fmaf(e2, e2, e3 * e3)))
                  + fmaf(e4, e4, fmaf(e5, e5, fmaf(e6, e6, e7 * e7)));
        float mxa = fmaxf(fmaxf(fmaxf(e0, e1), fmaxf(e2, e3)),
                          fmaxf(fmaxf(e4, e5), fmaxf(e6, e7)));
        float mna = fminf(fminf(fminf(e0, e1), fminf(e2, e3)),
                          fminf(fminf(e4, e5), fminf(e6, e7)));
        float s1b = ((e8 + e9) + (e10 + e11)) + ((e12 + e13) + (e14 + e15));
        float s2b = fmaf(e8, e8, fmaf(e9, e9, fmaf(e10, e10, e11 * e11)))
                  + fmaf(e12, e12, fmaf(e13, e13, fmaf(e14, e14, e15 * e15)));
        float mxb = fmaxf(fmaxf(fmaxf(e8, e9), fmaxf(e10, e11)),
                          fmaxf(fmaxf(e12, e13), fmaxf(e14, e15)));
        float mnb = fminf(fminf(fminf(e8, e9), fminf(e10, e11)),
                          fminf(fminf(e12, e13), fminf(e14, e15)));

        s1a += __shfl_xor(s1a, 32); s2a += __shfl_xor(s2a, 32);
        mxa = fmaxf(mxa, __shfl_xor(mxa, 32)); mna = fminf(mna, __shfl_xor(mna, 32));
        s1b += __shfl_xor(s1b, 32); s2b += __shfl_xor(s2b, 32);
        mxb = fmaxf(mxb, __shfl_xor(mxb, 32)); mnb = fminf(mnb, __shfl_xor(mnb, 32));

        float S1 = h2 ? s1b : s1a;
        float S2 = h2 ? s2b : s2a;
        float MX = h2 ? mxb : mxa;
        float MN = h2 ? mnb : mna;
        float M  = S1 * 0.0625f;
        float SD = sqrtf(fmaxf(fmaf(-M, M, S2 * 0.0625f), 0.f) + 1e-5f);

        unsigned short* pd = &A_lds[(2 * rt + h2) * ASTRIDE + 64 + colb];
        pd[0]   = f2bfh(M);
        pd[64]  = f2bfh(MX);
        pd[128] = f2bfh(MN);
        pd[192] = f2bfh(SD);
    }

    // ---- stage h (bf16) into A_lds h region (after tiles, before barrier 1) ----
    {
        int r = t >> 4, q = t & 15;
        us4 o;
        o.x = f2bfh(hv.x); o.y = f2bfh(hv.y); o.z = f2bfh(hv.z); o.w = f2bfh(hv.w);
        *(us4*)&A_lds[r * ASTRIDE + q * 4] = o;
    }

    // ---- hoist post1 weight loads (latency hides under barrier wait) ----
    s16x8 wf[10];
    #pragma unroll
    for (int ks = 0; ks < 10; ++ks)
        wf[ks] = *(const s16x8*)&wfullT[col16 * 320 + ks * 32 + g * 8];
    __syncthreads();   // barrier 1: agg + h visible

    // ---- post1: y1 = relu([h,agg]@Wfull + b1), K=320 ----
    {
        f32x4 y1 = {0.f, 0.f, 0.f, 0.f};
        #pragma unroll
        for (int ks = 0; ks < 10; ++ks) {
            s16x8 a = *(const s16x8*)&A_lds[c * ASTRIDE + ks * 32 + g * 8];
            y1 = __builtin_amdgcn_mfma_f32_16x16x32_bf16(a, wf[ks], y1, 0, 0, 0);
        }
        #pragma unroll
        for (int i = 0; i < 4; ++i)
            y1_lds[(g * 4 + i) * YSTRIDE + col16] = f2bfh(fmaxf(y1[i] + b1c, 0.f));
    }

    // ---- hoist post2 weight loads ----
    s16x8 wp0 = *(const s16x8*)&wp2T[col16 * 64 + 0 * 32 + g * 8];
    s16x8 wp1 = *(const s16x8*)&wp2T[col16 * 64 + 1 * 32 + g * 8];
    __syncthreads();   // barrier 2: y1 visible

    // ---- post2 + residual (h re-read from global; L1-warm) ----
    {
        f32x4 o = {0.f, 0.f, 0.f, 0.f};
        s16x8 a0 = *(const s16x8*)&y1_lds[c * YSTRIDE + 0 * 32 + g * 8];
        s16x8 a1 = *(const s16x8*)&y1_lds[c * YSTRIDE + 1 * 32 + g * 8];
        o = __builtin_amdgcn_mfma_f32_16x16x32_bf16(a0, wp0, o, 0, 0, 0);
        o = __builtin_amdgcn_mfma_f32_16x16x32_bf16(a1, wp1, o, 0, 0, 0);
        #pragma unroll
        for (int i = 0; i < 4; ++i) {
            int r = g * 4 + i;
            out[(node0 + r) * 64 + col16] =
                o[i] + b2c + h[(node0 + r) * 64 + col16];
        }
    }
}

extern "C" void kernel_launch(void* const* d_in, const int* in_sizes, int n_in,
                              void* d_out, int out_size, void* d_ws, size_t ws_size,
                              hipStream_t stream) {
    const float* h         = (const float*)d_in[0];
    const float* edge_attr = (const float*)d_in[1];
    const int*   nbr_idx   = (const int*)d_in[2];
    const float* W_pre     = (const float*)d_in[3];
    const float* b_pre     = (const float*)d_in[4];
    const float* W_post1   = (const float*)d_in[5];
    const float* b_post1   = (const float*)d_in[6];
    const float* W_post2   = (const float*)d_in[7];
    const float* b_post2   = (const float*)d_in[8];
    float* out = (float*)d_out;

    size_t need = (size_t)N_NODES * 64           // u8
                + (size_t)N_NODES * 64 * 2       // v bf16
                + (64 * 320 + 64 * 16 + 64 * 64) * 2;
    if (ws_size < need) return;   // ~12.05 MiB
    unsigned char*  u8p    = (unsigned char*)d_ws;                      // [N][64] u8
    unsigned short* vbf    = (unsigned short*)(u8p + (size_t)N_NODES * 64);  // [N][64] bf16
    unsigned short* wfullT = vbf + (size_t)N_NODES * 64;                // [64][320]
    unsigned short* w3T    = wfullT + 64 * 320;                         // [64][16]
    unsigned short* wp2T   = w3T + 64 * 16;                             // [64][64]

    double ld = log(16.0 + 1.0);                          // log(D+1)
    const double AVG = 2.302585092994046;
    float c1 = (float)(ld / AVG);
    float c2 = (float)(AVG / ld);

    k_prep<<<GRID_PREP, 256, 0, stream>>>(h, W_pre, b_pre, W_post1, W_post2,
                                          u8p, vbf, wfullT, w3T, wp2T, c1, c2);
    k_main<<<NBLK, 256, 0, stream>>>(h, edge_attr, nbr_idx, b_post1, b_post2,
                                     u8p, vbf, wfullT, w3T, wp2T, out);
}

// Round 20
// 60.034 us; speedup vs baseline: 3.3938x; 1.2081x over previous
//
#include <hip/hip_runtime.h>
#include <hip/hip_bf16.h>
#include <math.h>

// PNA layer, R20 = exact revert to R13 (verified session-best, 60.1 us).
//   u = h@W1 + b_pre  -> stored round(u*16)+128 as u8; decode cvt_f32_ubyte+fmaf
//   v = h@W2 (bf16)
//   per 16-node block (256 edges):
//     per 32x32 tile: acc = mfma32x32x16(ea_bf16, W3, 0)
//     e = relu(fmaf(u8, 1/16, acc + (v-8)));  agg = [mean,max,min,std] over d
//     y1 = relu([h,agg]@Wfull + b_post1);  out = y1@W_post2 + b_post2 + h
// MFMA layouts:
//   16x16x32 (m89-verified): A row=lane&15,k=(lane>>4)*8+j; B col=lane&15 same k;
//                            C col=lane&15,row=(lane>>4)*4+reg
//   32x32x16 (C/D m74/m101-verified): A row=lane&31,k=(lane>>5)*8+j;
//                            B col=lane&31,k=(lane>>5)*8+j;
//                            C col=lane&31,row=(reg&3)+8*(reg>>2)+4*(lane>>5)

#define N_NODES 65536
#define NBLK (N_NODES / 16)       // 4096 main/uv blocks
#define GRID_PREP (NBLK + 64)     // + 64 weight-transpose blocks
#define ASTRIDE 348   // A_lds row stride (u16)
#define YSTRIDE 76    // y1_lds row stride (u16)

typedef float f32x4 __attribute__((ext_vector_type(4)));
typedef float f32x16 __attribute__((ext_vector_type(16)));
typedef short s16x8 __attribute__((ext_vector_type(8)));
typedef unsigned short us4 __attribute__((ext_vector_type(4)));
typedef int i32x4 __attribute__((ext_vector_type(4)));

__device__ __forceinline__ unsigned short f2bf(float f) {     // manual RNE
    union { float f; unsigned int u; } v; v.f = f;
    unsigned int r = v.u + 0x7fffu + ((v.u >> 16) & 1u);
    return (unsigned short)(r >> 16);
}
__device__ __forceinline__ unsigned short f2bfh(float f) {    // compiler cvt
    __hip_bfloat16 b = __float2bfloat16(f);
    union { __hip_bfloat16 b; unsigned short u; } v; v.b = b; return v.u;
}
__device__ __forceinline__ float bf2f(unsigned short u) {
    union { unsigned int u; float f; } v; v.u = ((unsigned int)u) << 16; return v.f;
}
__device__ __forceinline__ unsigned char enc_u8(float x) {    // offset-int8, scale 16
    int q = __float2int_rn(x * 16.f) + 128;
    q = q < 0 ? 0 : (q > 255 ? 255 : q);
    return (unsigned char)q;
}

// ---------------- prep: u/v via MFMA (blocks < NBLK) + weight transpose ----------------
__global__ __launch_bounds__(256) void k_prep(const float* __restrict__ h,
                                              const float* __restrict__ Wpre,
                                              const float* __restrict__ b_pre,
                                              const float* __restrict__ Wp1,
                                              const float* __restrict__ Wp2,
                                              unsigned char* __restrict__ u8,
                                              unsigned short* __restrict__ vbf,
                                              unsigned short* __restrict__ wfullT,
                                              unsigned short* __restrict__ w3T,
                                              unsigned short* __restrict__ wp2T,
                                              float c1, float c2) {
    int t = threadIdx.x;
    if (blockIdx.x >= NBLK) {
        int c = blockIdx.x - NBLK;     // output col 0..63
        for (int k = t; k < 320; k += 256) {
            float v;
            if (k < 64) v = Wp1[k * 64 + c];
            else {
                int kk = k - 64;
                v = Wp1[(64 + kk) * 64 + c] + c1 * Wp1[(320 + kk) * 64 + c]
                                            + c2 * Wp1[(576 + kk) * 64 + c];
            }
            wfullT[c * 320 + k] = f2bf(v);
        }
        if (t < 16)              w3T[c * 16 + t]         = f2bf(Wpre[(128 + t) * 64 + c]);
        if (t >= 64 && t < 128)  wp2T[c * 64 + (t - 64)] = f2bf(Wp2[(t - 64) * 64 + c]);
        return;
    }

    // ---- uv blocks: [u|v] = h @ [W1|W2], 16 nodes, 4 waves x 32 cols ----
    __shared__ unsigned short hl[16 * 68];
    int lane = t & 63;
    int wv = __builtin_amdgcn_readfirstlane(t) >> 6;   // wave id (uniform)
    int c = lane & 15, g = lane >> 4;
    int node0 = blockIdx.x * 16;
    {
        int r = t >> 4, q = t & 15;
        float4 hv = *((const float4*)(h + (size_t)node0 * 64) + t);
        us4 o;
        o.x = f2bfh(hv.x); o.y = f2bfh(hv.y); o.z = f2bfh(hv.z); o.w = f2bfh(hv.w);
        *(us4*)&hl[r * 68 + q * 4] = o;
    }
    s16x8 bf[2][2];
    int woff = (wv < 2) ? 0 : 64;
    #pragma unroll
    for (int i2 = 0; i2 < 2; ++i2) {
        int wcol = ((wv & 1) * 32) + i2 * 16 + c;
        #pragma unroll
        for (int ks = 0; ks < 2; ++ks) {
            #pragma unroll
            for (int j = 0; j < 8; ++j)
                bf[i2][ks][j] = (short)f2bfh(Wpre[(woff + ks * 32 + g * 8 + j) * 64 + wcol]);
        }
    }
    __syncthreads();
    f32x4 acc0 = {0.f, 0.f, 0.f, 0.f}, acc1 = {0.f, 0.f, 0.f, 0.f};
    #pragma unroll
    for (int ks = 0; ks < 2; ++ks) {
        s16x8 a = *(const s16x8*)&hl[c * 68 + ks * 32 + g * 8];
        acc0 = __builtin_amdgcn_mfma_f32_16x16x32_bf16(a, bf[0][ks], acc0, 0, 0, 0);
        acc1 = __builtin_amdgcn_mfma_f32_16x16x32_bf16(a, bf[1][ks], acc1, 0, 0, 0);
    }
    #pragma unroll
    for (int i2 = 0; i2 < 2; ++i2) {
        int dcol = ((wv & 1) * 32) + i2 * 16 + c;
        const f32x4& av = i2 ? acc1 : acc0;
        if (wv < 2) {
            float bp = b_pre[dcol];
            #pragma unroll
            for (int i = 0; i < 4; ++i) {
                int row = g * 4 + i;
                u8[(size_t)(node0 + row) * 64 + dcol] = enc_u8(av[i] + bp);
            }
        } else {
            #pragma unroll
            for (int i = 0; i < 4; ++i) {
                int row = g * 4 + i;
                vbf[(size_t)(node0 + row) * 64 + dcol] = f2bfh(av[i]);
            }
        }
    }
}

// ---------------- fused main: one 16-node group per block ----------------
__global__ __launch_bounds__(256, 4) void k_main(
    const float* __restrict__ h,
    const float* __restrict__ edge_attr,
    const int* __restrict__ nbr_idx,
    const float* __restrict__ b_post1,
    const float* __restrict__ b_post2,
    const unsigned char* __restrict__ u8,       // [N][64] offset-int8 (4 MB, L2-fit)
    const unsigned short* __restrict__ vbf,     // [N][64] bf16
    const unsigned short* __restrict__ wfullT,  // [64][320] bf16 (L2-resident)
    const unsigned short* __restrict__ w3T,     // [64][16]
    const unsigned short* __restrict__ wp2T,    // [64][64]
    float* __restrict__ out) {
    __shared__ unsigned short A_lds[16 * ASTRIDE];   // 11136 B
    __shared__ unsigned short y1_lds[16 * YSTRIDE];  // 2432 B
    __shared__ int nbl[256];                         // 1024 B (byte offsets j<<6)

    int t = threadIdx.x;
    int lane = t & 63;
    int wu2 = __builtin_amdgcn_readfirstlane(t) >> 6;   // wave id (uniform)
    int c = lane & 15;          // 16x16 frag col / A-row
    int g = lane >> 4;          // 16x16 k-group
    int l32 = lane & 31;        // 32x32 frag row/col
    int h2 = lane >> 5;         // 32x32 k-half
    int ct = wu2 & 1;           // 32-col tile (uniform)
    int wr = wu2 >> 1;          // row-tile base (uniform)
    int colb = ct * 32 + l32;   // pretrans output col
    unsigned cbu = (unsigned)colb;         // byte offset within 64B u8 row
    unsigned cb2 = (unsigned)(colb * 2);   // byte offset within 128B v row
    int col16 = wu2 * 16 + c;   // post1/post2 output col
    int node0 = blockIdx.x * 16;

    s16x8 w3b = *(const s16x8*)&w3T[colb * 16 + h2 * 8];
    float b1c = b_post1[col16];
    float b2c = b_post2[col16];

    // ---- stage h (bf16) into A_lds + neighbor byte-offsets ----
    {
        int r = t >> 4, q = t & 15;
        float4 hv = *((const float4*)(h + (size_t)node0 * 64) + t);
        us4 o;
        o.x = f2bfh(hv.x); o.y = f2bfh(hv.y); o.z = f2bfh(hv.z); o.w = f2bfh(hv.w);
        *(us4*)&A_lds[r * ASTRIDE + q * 4] = o;
        nbl[t] = nbr_idx[node0 * 16 + t] << 6;   // byte offset of u8 row
    }
    __syncthreads();

    const unsigned char* ub = u8;
    const char* vb = (const char*)vbf + ((unsigned)node0 << 7) + (unsigned)(wr * 256) + cb2;
    const char* eb = (const char*)edge_attr
                   + ((size_t)node0 * 16 + wr * 32 + l32) * 64 + h2 * 32;

    // ---- pretrans: 4x 32x32x16 MFMA tiles; u/v added AFTER the MFMA ----
    #pragma unroll
    for (int it = 0; it < 4; ++it) {
        int rt = wr + 2 * it;                    // row-tile 0..7 (uniform)

        // A-frag from global fp32 (independent of gather)
        float4 x0 = *(const float4*)(eb + it * 4096);
        float4 x1 = *(const float4*)(eb + it * 4096 + 16);
        s16x8 a;
        a[0] = (short)f2bfh(x0.x); a[1] = (short)f2bfh(x0.y);
        a[2] = (short)f2bfh(x0.z); a[3] = (short)f2bfh(x0.w);
        a[4] = (short)f2bfh(x1.x); a[5] = (short)f2bfh(x1.y);
        a[6] = (short)f2bfh(x1.z); a[7] = (short)f2bfh(x1.w);

        f32x16 acc = {};
        acc = __builtin_amdgcn_mfma_f32_32x32x16_bf16(a, w3b, acc, 0, 0, 0);

        // gathered u8 (16 scalar 1B loads, issued in parallel with the MFMA)
        i32x4 jq0 = *(const i32x4*)&nbl[rt * 32 + 4 * h2 + 0];
        i32x4 jq1 = *(const i32x4*)&nbl[rt * 32 + 4 * h2 + 8];
        i32x4 jq2 = *(const i32x4*)&nbl[rt * 32 + 4 * h2 + 16];
        i32x4 jq3 = *(const i32x4*)&nbl[rt * 32 + 4 * h2 + 24];
        float uf[16];
        #pragma unroll
        for (int i = 0; i < 4; ++i) {
            uf[i]      = (float)ub[(unsigned)jq0[i] + cbu];
            uf[4 + i]  = (float)ub[(unsigned)jq1[i] + cbu];
            uf[8 + i]  = (float)ub[(unsigned)jq2[i] + cbu];
            uf[12 + i] = (float)ub[(unsigned)jq3[i] + cbu];
        }
        float vm0 = bf2f(*(const unsigned short*)(vb + it * 512)) - 8.f;
        float vm1 = bf2f(*(const unsigned short*)(vb + it * 512 + 128)) - 8.f;

        // e = relu(acc + u + v) with u = uf/16 - 8 folded via fmaf
        float e0  = fmaxf(fmaf(uf[0],  0.0625f, acc[0]  + vm0), 0.f);
        float e1  = fmaxf(fmaf(uf[1],  0.0625f, acc[1]  + vm0), 0.f);
        float e2  = fmaxf(fmaf(uf[2],  0.0625f, acc[2]  + vm0), 0.f);
        float e3  = fmaxf(fmaf(uf[3],  0.0625f, acc[3]  + vm0), 0.f);
        float e4  = fmaxf(fmaf(uf[4],  0.0625f, acc[4]  + vm0), 0.f);
        float e5  = fmaxf(fmaf(uf[5],  0.0625f, acc[5]  + vm0), 0.f);
        float e6  = fmaxf(fmaf(uf[6],  0.0625f, acc[6]  + vm0), 0.f);
        float e7  = fmaxf(fmaf(uf[7],  0.0625f, acc[7]  + vm0), 0.f);
        float e8  = fmaxf(fmaf(uf[8],  0.0625f, acc[8]  + vm1), 0.f);
        float e9  = fmaxf(fmaf(uf[9],  0.0625f, acc[9]  + vm1), 0.f);
        float e10 = fmaxf(fmaf(uf[10], 0.0625f, acc[10] + vm1), 0.f);
        float e11 = fmaxf(fmaf(uf[11], 0.0625f, acc[11] + vm1), 0.f);
        float e12 = fmaxf(fmaf(uf[12], 0.0625f, acc[12] + vm1), 0.f);
        float e13 = fmaxf(fmaf(uf[13], 0.0625f, acc[13] + vm1), 0.f);
        float e14 = fmaxf(fmaf(uf[14], 0.0625f, acc[14] + vm1), 0.f);
        float e15 = fmaxf(fmaf(uf[15], 0.0625f, acc[15] + vm1), 0.f);

        float s1a = ((e0 + e1) + (e2 + e3)) + ((e4 + e5) + (e6 + e7));
        float s2a = fmaf(e0, e0, fmaf(e1, e1, fmaf(e2, e2, e3 * e3)))
                  + fmaf(e4, e4, fmaf(e5, e5, fmaf(e6, e6, e7 * e7)));
        float mxa = fmaxf(fmaxf(fmaxf(e0, e1), fmaxf(e2, e3)),
                          fmaxf(fmaxf(e4, e5), fmaxf(e6, e7)));
        float mna = fminf(fminf(fminf(e0, e1), fminf(e2, e3)),
                          fminf(fminf(e4, e5), fminf(e6, e7)));
        float s1b = ((e8 + e9) + (e10 + e11)) + ((e12 + e13) + (e14 + e15));
        float s2b = fmaf(e8, e8, fmaf(e9, e9, fmaf(e10, e10, e11 * e11)))
                  + fmaf(e12, e12, fmaf(e13, e13, fmaf(e14, e14, e15 * e15)));
        float mxb = fmaxf(fmaxf(fmaxf(e8, e9), fmaxf(e10, e11)),
                          fmaxf(fmaxf(e12, e13), fmaxf(e14, e15)));
        float mnb = fminf(fminf(fminf(e8, e9), fminf(e10, e11)),
                          fminf(fminf(e12, e13), fminf(e14, e15)));

        s1a += __shfl_xor(s1a, 32); s2a += __shfl_xor(s2a, 32);
        mxa = fmaxf(mxa, __shfl_xor(mxa, 32)); mna = fminf(mna, __shfl_xor(mna, 32));
        s1b += __shfl_xor(s1b, 32); s2b += __shfl_xor(s2b, 32);
        mxb = fmaxf(mxb, __shfl_xor(mxb, 32)); mnb = fminf(mnb, __shfl_xor(mnb, 32));

        float S1 = h2 ? s1b : s1a;
        float S2 = h2 ? s2b : s2a;
        float MX = h2 ? mxb : mxa;
        float MN = h2 ? mnb : mna;
        float M  = S1 * 0.0625f;
        float SD = sqrtf(fmaxf(fmaf(-M, M, S2 * 0.0625f), 0.f) + 1e-5f);

        unsigned short* pd = &A_lds[(2 * rt + h2) * ASTRIDE + 64 + colb];
        pd[0]   = f2bfh(M);
        pd[64]  = f2bfh(MX);
        pd[128] = f2bfh(MN);
        pd[192] = f2bfh(SD);
    }

    // ---- hoist post1 weight loads (latency hides under barrier wait) ----
    s16x8 wf[10];
    #pragma unroll
    for (int ks = 0; ks < 10; ++ks)
        wf[ks] = *(const s16x8*)&wfullT[col16 * 320 + ks * 32 + g * 8];
    __syncthreads();

    // ---- post1: y1 = relu([h,agg]@Wfull + b1), K=320 ----
    {
        f32x4 y1 = {0.f, 0.f, 0.f, 0.f};
        #pragma unroll
        for (int ks = 0; ks < 10; ++ks) {
            s16x8 a = *(const s16x8*)&A_lds[c * ASTRIDE + ks * 32 + g * 8];
            y1 = __builtin_amdgcn_mfma_f32_16x16x32_bf16(a, wf[ks], y1, 0, 0, 0);
        }
        #pragma unroll
        for (int i = 0; i < 4; ++i)
            y1_lds[(g * 4 + i) * YSTRIDE + col16] = f2bfh(fmaxf(y1[i] + b1c, 0.f));
    }

    // ---- hoist post2 weight loads ----
    s16x8 wp0 = *(const s16x8*)&wp2T[col16 * 64 + 0 * 32 + g * 8];
    s16x8 wp1 = *(const s16x8*)&wp2T[col16 * 64 + 1 * 32 + g * 8];
    __syncthreads();

    // ---- post2 + residual (h re-read from global; L1-warm) ----
    {
        f32x4 o = {0.f, 0.f, 0.f, 0.f};
        s16x8 a0 = *(const s16x8*)&y1_lds[c * YSTRIDE + 0 * 32 + g * 8];
        s16x8 a1 = *(const s16x8*)&y1_lds[c * YSTRIDE + 1 * 32 + g * 8];
        o = __builtin_amdgcn_mfma_f32_16x16x32_bf16(a0, wp0, o, 0, 0, 0);
        o = __builtin_amdgcn_mfma_f32_16x16x32_bf16(a1, wp1, o, 0, 0, 0);
        #pragma unroll
        for (int i = 0; i < 4; ++i) {
            int r = g * 4 + i;
            out[(size_t)(node0 + r) * 64 + col16] =
                o[i] + b2c + h[(size_t)(node0 + r) * 64 + col16];
        }
    }
}

extern "C" void kernel_launch(void* const* d_in, const int* in_sizes, int n_in,
                              void* d_out, int out_size, void* d_ws, size_t ws_size,
                              hipStream_t stream) {
    const float* h         = (const float*)d_in[0];
    const float* edge_attr = (const float*)d_in[1];
    const int*   nbr_idx   = (const int*)d_in[2];
    const float* W_pre     = (const float*)d_in[3];
    const float* b_pre     = (const float*)d_in[4];
    const float* W_post1   = (const float*)d_in[5];
    const float* b_post1   = (const float*)d_in[6];
    const float* W_post2   = (const float*)d_in[7];
    const float* b_post2   = (const float*)d_in[8];
    float* out = (float*)d_out;

    size_t need = (size_t)N_NODES * 64           // u8
                + (size_t)N_NODES * 64 * 2       // v bf16
                + (64 * 320 + 64 * 16 + 64 * 64) * 2;
    if (ws_size < need) return;   // ~12.05 MiB
    unsigned char*  u8p    = (unsigned char*)d_ws;                      // [N][64] u8
    unsigned short* vbf    = (unsigned short*)(u8p + (size_t)N_NODES * 64);  // [N][64] bf16
    unsigned short* wfullT = vbf + (size_t)N_NODES * 64;                // [64][320]
    unsigned short* w3T    = wfullT + 64 * 320;                         // [64][16]
    unsigned short* wp2T   = w3T + 64 * 16;                             // [64][64]

    double ld = log(16.0 + 1.0);                          // log(D+1)
    const double AVG = 2.302585092994046;
    float c1 = (float)(ld / AVG);
    float c2 = (float)(AVG / ld);

    k_prep<<<GRID_PREP, 256, 0, stream>>>(h, W_pre, b_pre, W_post1, W_post2,
                                          u8p, vbf, wfullT, w3T, wp2T, c1, c2);
    k_main<<<NBLK, 256, 0, stream>>>(h, edge_attr, nbr_idx, b_post1, b_post2,
                                     u8p, vbf, wfullT, w3T, wp2T, out);
}